// Round 1
// baseline (1302.472 us; speedup 1.0000x reference)
//
#include <hip/hip_runtime.h>

// Segmented sum: out[2*b + m][:] += node_rep[i][:] for seg of node i.
// batch_ids is SORTED -> contiguous runs; accumulate in registers per wave,
// flush with atomics only on batch-id change / chunk boundary.

constexpr int WAVE = 64;
constexpr int D2   = 64;   // 128 floats = 64 float2 per row
constexpr int PF   = 8;    // loads in flight per wave

__global__ __launch_bounds__(256) void seg_pool_kernel(
    const float2* __restrict__ data,     // node_rep as float2 [N*64]
    const int*    __restrict__ batch_ids,
    const int*    __restrict__ mol_idx,
    float*        __restrict__ out,      // [2B * 128], pre-zeroed
    int N, int nodes_per_wave)
{
    const int gtid    = blockIdx.x * blockDim.x + threadIdx.x;
    const int wave_id = gtid >> 6;
    const int lane    = threadIdx.x & 63;

    long start = (long)wave_id * nodes_per_wave;
    if (start >= N) return;
    long end = start + nodes_per_wave;
    if (end > N) end = N;

    float2 acc0 = {0.f, 0.f};   // mol_idx == 0 accumulator (2 cols/lane)
    float2 acc1 = {0.f, 0.f};   // mol_idx == 1 accumulator
    int cur_b = -1;

    auto flush = [&]() {
        if (cur_b >= 0) {
            size_t o = (size_t)(2 * cur_b) * 128 + 2 * lane;
            atomicAdd(out + o,       acc0.x);
            atomicAdd(out + o + 1,   acc0.y);
            atomicAdd(out + o + 128, acc1.x);
            atomicAdd(out + o + 129, acc1.y);
        }
        acc0 = {0.f, 0.f};
        acc1 = {0.f, 0.f};
    };

    long base = start;
    // Full 64-node stages: coalesced id staging + shfl broadcast.
    for (; base + WAVE <= end; base += WAVE) {
        int seg = batch_ids[base + lane] * 2 + mol_idx[base + lane];
        #pragma unroll
        for (int j0 = 0; j0 < WAVE; j0 += PF) {
            float2 v[PF];
            #pragma unroll
            for (int u = 0; u < PF; ++u)
                v[u] = data[(size_t)(base + j0 + u) * D2 + lane];
            #pragma unroll
            for (int u = 0; u < PF; ++u) {
                int s = __shfl(seg, j0 + u);
                int b = s >> 1;
                if (b != cur_b) { flush(); cur_b = b; }   // wave-uniform, rare
                if (s & 1) { acc1.x += v[u].x; acc1.y += v[u].y; }
                else       { acc0.x += v[u].x; acc0.y += v[u].y; }
            }
        }
    }
    // Tail (< 64 nodes)
    int rem = (int)(end - base);
    if (rem > 0) {
        int seg = 0;
        if (lane < rem) seg = batch_ids[base + lane] * 2 + mol_idx[base + lane];
        for (int j = 0; j < rem; ++j) {
            int s = __shfl(seg, j);
            int b = s >> 1;
            if (b != cur_b) { flush(); cur_b = b; }
            float2 v = data[(size_t)(base + j) * D2 + lane];
            if (s & 1) { acc1.x += v.x; acc1.y += v.y; }
            else       { acc0.x += v.x; acc0.y += v.y; }
        }
    }
    flush();
}

extern "C" void kernel_launch(void* const* d_in, const int* in_sizes, int n_in,
                              void* d_out, int out_size, void* d_ws, size_t ws_size,
                              hipStream_t stream) {
    const float2* node_rep = (const float2*)d_in[0];
    const int* batch_ids   = (const int*)d_in[1];
    const int* mol_idx     = (const int*)d_in[2];
    float* out             = (float*)d_out;

    const int N = in_sizes[1];   // batch_ids element count == node count

    // Output is re-poisoned to 0xAA before every timed launch -> zero it.
    hipMemsetAsync(d_out, 0, (size_t)out_size * sizeof(float), stream);

    const int total_waves    = 4096;                 // 16 waves/CU
    const int nodes_per_wave = (N + total_waves - 1) / total_waves;
    const int threads        = 256;                  // 4 waves/block
    const int blocks         = total_waves / (threads / WAVE);

    seg_pool_kernel<<<blocks, threads, 0, stream>>>(
        node_rep, batch_ids, mol_idx, out, N, nodes_per_wave);
}